// Round 4
// baseline (776.814 us; speedup 1.0000x reference)
//
#include <hip/hip_runtime.h>

#define B_ 4
#define T_ 2048
#define D_ 1024
#define H_ 16
#define DK_ 64
#define M_ (B_*T_)   // 8192

typedef __attribute__((ext_vector_type(4))) float f32x4;
typedef __attribute__((ext_vector_type(8))) short s16x8;
typedef unsigned short u16t;
typedef unsigned int   u32t;
typedef unsigned long long u64t;

__device__ __forceinline__ u16t f2bf(float x){
  u32t u = __float_as_uint(x);
  return (u16t)((u + 0x7FFFu + ((u >> 16) & 1u)) >> 16);
}

__device__ __forceinline__ f32x4 mfma16(s16x8 a, s16x8 b, f32x4 c){
  return __builtin_amdgcn_mfma_f32_16x16x32_bf16(a, b, c, 0, 0, 0);
}

// async global->LDS, 16B per lane; LDS dest = wave-uniform base + lane*16
__device__ __forceinline__ void gload16(const void* g, void* l){
  __builtin_amdgcn_global_load_lds(
      (const __attribute__((address_space(1))) u32t*)g,
      (__attribute__((address_space(3))) u32t*)l, 16, 0, 0);
}

// ---------------- fp32 -> bf16 convert ----------------
__global__ __launch_bounds__(256) void cvt_bf16(const float* __restrict__ src,
                                                u16t* __restrict__ dst, int n4){
  int i = blockIdx.x * 256 + threadIdx.x;
  if (i < n4){
    float4 v = ((const float4*)src)[i];
    u64t o = (u64t)f2bf(v.x) | ((u64t)f2bf(v.y) << 16)
           | ((u64t)f2bf(v.z) << 32) | ((u64t)f2bf(v.w) << 48);
    ((u64t*)dst)[i] = o;
  }
}

// ---------------- GEMM: C[m][n] = sum_k A[m][k]*Bw[n][k] + bias[n] ----------------
// 128x128 tile, BK=32, 4 waves (2x2), 16x16x32 bf16 MFMA, global_load_lds w16.
// OT = u16t (bf16 out, intermediates) or float (fp32 out, final projection).
#define BM 128
#define BN 128
#define BKG 32

template<typename OT>
__global__ __launch_bounds__(256, 2) void gemm_bt(const u16t* __restrict__ A,
                                                  const u16t* __restrict__ Bw,
                                                  const float* __restrict__ bias,
                                                  OT* __restrict__ C,
                                                  int Mi, int Ni, int Ki){
  __shared__ u16t As[BM * BKG];   // 8 KB, linear [row][k] (64B rows)
  __shared__ u16t Bs[BN * BKG];
  const int tid = threadIdx.x, lane = tid & 63, w = tid >> 6;
  const int wm = w >> 1, wn = w & 1;
  const int bm = blockIdx.x * BM, bn = blockIdx.y * BN;

  f32x4 acc[4][4];
  const f32x4 z4 = {0.f, 0.f, 0.f, 0.f};
  #pragma unroll
  for (int i = 0; i < 4; i++)
    #pragma unroll
    for (int j = 0; j < 4; j++) acc[i][j] = z4;

  for (int kk = 0; kk < Ki; kk += BKG){
    #pragma unroll
    for (int i = 0; i < 2; i++){
      int y   = (w * 2 + i) * 1024 + lane * 16;   // linear byte in 8KB tile
      int row = y >> 6;                            // 64B per row (32 bf16)
      int ke  = (y >> 4) & 3;                      // 16B chunk within row
      gload16(A  + (size_t)(bm + row) * Ki + kk + ke * 8, (char*)As + (w * 2 + i) * 1024);
      gload16(Bw + (size_t)(bn + row) * Ki + kk + ke * 8, (char*)Bs + (w * 2 + i) * 1024);
    }
    __syncthreads();
    s16x8 af[4], bf[4];
    #pragma unroll
    for (int i = 0; i < 4; i++){
      af[i] = *(const s16x8*)(As + (size_t)(wm * 64 + i * 16 + (lane & 15)) * BKG + (lane >> 4) * 8);
      bf[i] = *(const s16x8*)(Bs + (size_t)(wn * 64 + i * 16 + (lane & 15)) * BKG + (lane >> 4) * 8);
    }
    #pragma unroll
    for (int i = 0; i < 4; i++)
      #pragma unroll
      for (int j = 0; j < 4; j++)
        acc[i][j] = mfma16(af[i], bf[j], acc[i][j]);
    __syncthreads();
  }

  // epilogue: D layout col = lane&15, row = (lane>>4)*4 + r  (m91-verified)
  #pragma unroll
  for (int j = 0; j < 4; j++){
    int n = bn + wn * 64 + j * 16 + (lane & 15);
    float bv = bias[n];
    #pragma unroll
    for (int i = 0; i < 4; i++){
      int m0 = bm + wm * 64 + i * 16 + (lane >> 4) * 4;
      #pragma unroll
      for (int r = 0; r < 4; r++){
        float v = acc[i][j][r] + bv;
        if constexpr (sizeof(OT) == 4)
          C[(size_t)(m0 + r) * Ni + n] = v;
        else
          C[(size_t)(m0 + r) * Ni + n] = f2bf(v);
      }
    }
  }
}

// ---------------- V transpose: V[b][t][h*64+dk] -> Vt[(b*H+h)][dk][t] ----------------
__global__ __launch_bounds__(256) void transpose_v(const u16t* __restrict__ V,
                                                   u16t* __restrict__ Vt){
  __shared__ u16t tle[64][65];
  const int bh = blockIdx.y, b = bh >> 4, h = bh & 15;
  const int t0 = blockIdx.x * 64;
  const u16t* vp = V + (size_t)(b * T_ + t0) * D_ + h * DK_;
  #pragma unroll
  for (int i = 0; i < 16; i++){
    int idx = threadIdx.x + i * 256;
    int tr = idx >> 6, dk = idx & 63;
    tle[tr][dk] = vp[(size_t)tr * D_ + dk];
  }
  __syncthreads();
  u16t* op = Vt + (size_t)bh * DK_ * T_ + t0;
  #pragma unroll
  for (int i = 0; i < 16; i++){
    int idx = threadIdx.x + i * 256;
    int dk = idx >> 6, tr = idx & 63;
    op[(size_t)dk * T_ + tr] = tle[tr][dk];
  }
}

// ---------------- flash attention ----------------
// grid (T/128, B*H), 512 threads = 8 independent waves, 16 q-rows each.
// Swapped QK^T: S^T = mfma(Kfrag, Qfrag) -> lane owns column q = lane&15.
// mask: int32 per key (nonzero => masked). Confirmed by r2==r3 A/B.
__global__ __launch_bounds__(512) void attn(const u16t* __restrict__ Q,
                                            const u16t* __restrict__ K,
                                            const u16t* __restrict__ Vt,
                                            const int* __restrict__ mask,
                                            u16t* __restrict__ X){
  const int lane = threadIdx.x & 63;
  const int w = threadIdx.x >> 6;
  const int q16 = lane & 15, g = lane >> 4;
  const int bh = blockIdx.y, b = bh >> 4, h = bh & 15;
  const int tq = blockIdx.x * 128 + w * 16 + q16;

  const u16t* qp = Q + (size_t)(b * T_ + tq) * D_ + h * DK_ + g * 8;
  s16x8 qf0 = *(const s16x8*)(qp);
  s16x8 qf1 = *(const s16x8*)(qp + 32);

  const f32x4 z4 = {0.f, 0.f, 0.f, 0.f};
  f32x4 acc[4];
  #pragma unroll
  for (int d = 0; d < 4; d++) acc[d] = z4;
  float mrun = -1e30f, lsum = 0.f;

  const u16t* kbase = K + (size_t)b * T_ * D_ + h * DK_;
  const u16t* vbase = Vt + (size_t)bh * DK_ * T_;
  const int* mb = mask + (size_t)b * T_;

  for (int kt = 0; kt < T_; kt += 32){
    // S^T (32 k-rows x 16 q-cols): A = K rows (lane&15), B = Q cols (lane&15)
    const u16t* kp0 = kbase + (size_t)(kt + q16) * D_ + g * 8;
    const u16t* kp1 = kp0 + (size_t)16 * D_;
    s16x8 k00 = *(const s16x8*)(kp0);
    s16x8 k01 = *(const s16x8*)(kp0 + 32);
    s16x8 k10 = *(const s16x8*)(kp1);
    s16x8 k11 = *(const s16x8*)(kp1 + 32);
    f32x4 s0 = z4, s1 = z4;
    s0 = mfma16(k00, qf0, s0); s0 = mfma16(k01, qf1, s0);
    s1 = mfma16(k10, qf0, s1); s1 = mfma16(k11, qf1, s1);

    // mask (int32 per key) + scale; output row (k) = g*4 + r within 16-k subtile
    int4 mm0 = *(const int4*)(mb + kt + g * 4);
    int4 mm1 = *(const int4*)(mb + kt + 16 + g * 4);
    int mA[4] = {mm0.x, mm0.y, mm0.z, mm0.w};
    int mBv[4] = {mm1.x, mm1.y, mm1.z, mm1.w};
    float sv0[4], sv1[4];
    #pragma unroll
    for (int r = 0; r < 4; r++){
      sv0[r] = mA[r]  ? -3e38f : s0[r] * 0.125f;
      sv1[r] = mBv[r] ? -3e38f : s1[r] * 0.125f;
    }
    // online softmax state per q-column (2 shfl_xor reduces across lane groups)
    float mx = sv0[0];
    #pragma unroll
    for (int r = 1; r < 4; r++) mx = fmaxf(mx, sv0[r]);
    #pragma unroll
    for (int r = 0; r < 4; r++) mx = fmaxf(mx, sv1[r]);
    mx = fmaxf(mx, __shfl_xor(mx, 16, 64));
    mx = fmaxf(mx, __shfl_xor(mx, 32, 64));
    float mnew = fmaxf(mrun, mx);
    float fsc = __expf(mrun - mnew);
    float p0[4], p1[4], ts = 0.f;
    #pragma unroll
    for (int r = 0; r < 4; r++){
      p0[r] = __expf(sv0[r] - mnew);
      p1[r] = __expf(sv1[r] - mnew);
      ts += p0[r] + p1[r];
    }
    ts += __shfl_xor(ts, 16, 64);
    ts += __shfl_xor(ts, 32, 64);
    lsum = lsum * fsc + ts;
    mrun = mnew;
    #pragma unroll
    for (int d = 0; d < 4; d++) acc[d] = acc[d] * fsc;

    // Build PV B-fragment: lane needs P^T[k=g*8+j][q], j=0..7
    u32t w0a = ((u32t)f2bf(p0[1]) << 16) | f2bf(p0[0]);
    u32t w1a = ((u32t)f2bf(p0[3]) << 16) | f2bf(p0[2]);
    u32t w0b = ((u32t)f2bf(p1[1]) << 16) | f2bf(p1[0]);
    u32t w1b = ((u32t)f2bf(p1[3]) << 16) | f2bf(p1[2]);
    int laneA = ((g & 1) << 5) | q16;
    u32t a0 = (u32t)__shfl((int)w0a, laneA, 64);
    u32t a1 = (u32t)__shfl((int)w1a, laneA, 64);
    u32t a2 = (u32t)__shfl((int)w0b, laneA, 64);
    u32t a3 = (u32t)__shfl((int)w1b, laneA, 64);
    u32t b0 = (u32t)__shfl((int)w0a, laneA + 16, 64);
    u32t b1 = (u32t)__shfl((int)w1a, laneA + 16, 64);
    u32t b2 = (u32t)__shfl((int)w0b, laneA + 16, 64);
    u32t b3 = (u32t)__shfl((int)w1b, laneA + 16, 64);
    bool hi = (g >= 2);   // this lane's k-range lives in subtile 1
    union { u32t u[4]; s16x8 v; } pf;
    pf.u[0] = hi ? a2 : a0;
    pf.u[1] = hi ? a3 : a1;
    pf.u[2] = hi ? b2 : b0;
    pf.u[3] = hi ? b3 : b1;

    // PV: X^T[dk][q] += V^T[dk][k] * P^T[k][q]
    const u16t* vp = vbase + kt + g * 8;
    #pragma unroll
    for (int d = 0; d < 4; d++){
      s16x8 vf = *(const s16x8*)(vp + (size_t)(d * 16 + q16) * T_);
      acc[d] = mfma16(vf, pf.v, acc[d]);
    }
  }

  float inv = (lsum > 0.f) ? 1.0f / lsum : 0.f;
  // X[b][tq][h*64 + dk], dk = d*16 + g*4 + r
  u16t* xp = X + (size_t)(b * T_ + tq) * D_ + h * DK_ + g * 4;
  #pragma unroll
  for (int d = 0; d < 4; d++){
    u32t o0 = ((u32t)f2bf(acc[d][1] * inv) << 16) | f2bf(acc[d][0] * inv);
    u32t o1 = ((u32t)f2bf(acc[d][3] * inv) << 16) | f2bf(acc[d][2] * inv);
    *(u64t*)(xp + d * 16) = ((u64t)o1 << 32) | o0;
  }
}

extern "C" void kernel_launch(void* const* d_in, const int* in_sizes, int n_in,
                              void* d_out, int out_size, void* d_ws, size_t ws_size,
                              hipStream_t stream){
  (void)in_sizes; (void)n_in; (void)out_size; (void)ws_size;
  const float* query = (const float*)d_in[0];
  const float* key   = (const float*)d_in[1];
  const float* value = (const float*)d_in[2];
  const int*   mask  = (const int*)d_in[3];
  const float* wq = (const float*)d_in[4];
  const float* bq = (const float*)d_in[5];
  const float* wk = (const float*)d_in[6];
  const float* bk = (const float*)d_in[7];
  const float* wv = (const float*)d_in[8];
  const float* bv = (const float*)d_in[9];
  const float* wo = (const float*)d_in[10];
  const float* bo = (const float*)d_in[11];

  const size_t A = (size_t)M_ * D_;     // 8388608 elements
  const size_t W = (size_t)D_ * D_;     // 1048576
  u16t* ws  = (u16t*)d_ws;
  u16t* qb  = ws;
  u16t* kb  = ws + A;
  u16t* vb  = ws + 2 * A;
  u16t* Qm  = ws + 3 * A;
  u16t* Km  = ws + 4 * A;
  u16t* Vm  = ws + 5 * A;
  u16t* wqb = ws + 6 * A;
  u16t* wkb = wqb + W;
  u16t* wvb = wqb + 2 * W;
  u16t* wob = wqb + 3 * W;
  u16t* Vt  = qb;   // reuse: qb consumed by Q-proj before transpose runs
  u16t* Xm  = kb;   // reuse: kb consumed by K-proj before attention runs

  int nA4 = (int)(A / 4), nW4 = (int)(W / 4);
  cvt_bf16<<<nA4 / 256, 256, 0, stream>>>(query, qb, nA4);
  cvt_bf16<<<nA4 / 256, 256, 0, stream>>>(key,   kb, nA4);
  cvt_bf16<<<nA4 / 256, 256, 0, stream>>>(value, vb, nA4);
  cvt_bf16<<<nW4 / 256, 256, 0, stream>>>(wq, wqb, nW4);
  cvt_bf16<<<nW4 / 256, 256, 0, stream>>>(wk, wkb, nW4);
  cvt_bf16<<<nW4 / 256, 256, 0, stream>>>(wv, wvb, nW4);
  cvt_bf16<<<nW4 / 256, 256, 0, stream>>>(wo, wob, nW4);

  dim3 gg(M_ / BM, D_ / BN);
  gemm_bt<u16t><<<gg, 256, 0, stream>>>(qb, wqb, bq, Qm, M_, D_, D_);
  gemm_bt<u16t><<<gg, 256, 0, stream>>>(kb, wkb, bk, Km, M_, D_, D_);
  gemm_bt<u16t><<<gg, 256, 0, stream>>>(vb, wvb, bv, Vm, M_, D_, D_);

  transpose_v<<<dim3(T_ / 64, B_ * H_), 256, 0, stream>>>(Vm, Vt);

  attn<<<dim3(T_ / 128, B_ * H_), 512, 0, stream>>>(Qm, Km, Vt, mask, Xm);

  // final projection writes fp32 (reference output dtype is float32)
  gemm_bt<float><<<gg, 256, 0, stream>>>(Xm, wob, bo, (float*)d_out, M_, D_, D_);
}

// Round 5
// 457.940 us; speedup vs baseline: 1.6963x; 1.6963x over previous
//
#include <hip/hip_runtime.h>

#define B_ 4
#define T_ 2048
#define D_ 1024
#define H_ 16
#define DK_ 64
#define M_ (B_*T_)   // 8192

typedef __attribute__((ext_vector_type(4))) float f32x4;
typedef __attribute__((ext_vector_type(8))) short s16x8;
typedef unsigned short u16t;
typedef unsigned int   u32t;
typedef unsigned long long u64t;

__device__ __forceinline__ u16t f2bf(float x){
  u32t u = __float_as_uint(x);
  return (u16t)((u + 0x7FFFu + ((u >> 16) & 1u)) >> 16);
}

__device__ __forceinline__ f32x4 mfma16(s16x8 a, s16x8 b, f32x4 c){
  return __builtin_amdgcn_mfma_f32_16x16x32_bf16(a, b, c, 0, 0, 0);
}

// async global->LDS, 16B per lane; LDS dest = wave-uniform base + lane*16
__device__ __forceinline__ void gload16(const void* g, void* l){
  __builtin_amdgcn_global_load_lds(
      (const __attribute__((address_space(1))) u32t*)g,
      (__attribute__((address_space(3))) u32t*)l, 16, 0, 0);
}

// ---------------- fp32 -> bf16 convert ----------------
__global__ __launch_bounds__(256) void cvt_bf16(const float* __restrict__ src,
                                                u16t* __restrict__ dst, int n4){
  int i = blockIdx.x * 256 + threadIdx.x;
  if (i < n4){
    float4 v = ((const float4*)src)[i];
    u64t o = (u64t)f2bf(v.x) | ((u64t)f2bf(v.y) << 16)
           | ((u64t)f2bf(v.z) << 32) | ((u64t)f2bf(v.w) << 48);
    ((u64t*)dst)[i] = o;
  }
}

// ---------------- GEMM: C[m][n] = sum_k A[m][k]*Bw[n][k] + bias[n] ----------------
// 128x128 tile, BK=32, 4 waves (2x2), 16x16x32 bf16 MFMA, global_load_lds w16.
#define BM 128
#define BN 128
#define BKG 32

template<typename OT>
__global__ __launch_bounds__(256, 2) void gemm_bt(const u16t* __restrict__ A,
                                                  const u16t* __restrict__ Bw,
                                                  const float* __restrict__ bias,
                                                  OT* __restrict__ C,
                                                  int Mi, int Ni, int Ki){
  __shared__ u16t As[BM * BKG];   // 8 KB, linear [row][k] (64B rows)
  __shared__ u16t Bs[BN * BKG];
  const int tid = threadIdx.x, lane = tid & 63, w = tid >> 6;
  const int wm = w >> 1, wn = w & 1;
  const int bm = blockIdx.x * BM, bn = blockIdx.y * BN;

  f32x4 acc[4][4];
  const f32x4 z4 = {0.f, 0.f, 0.f, 0.f};
  #pragma unroll
  for (int i = 0; i < 4; i++)
    #pragma unroll
    for (int j = 0; j < 4; j++) acc[i][j] = z4;

  for (int kk = 0; kk < Ki; kk += BKG){
    #pragma unroll
    for (int i = 0; i < 2; i++){
      int y   = (w * 2 + i) * 1024 + lane * 16;   // linear byte in 8KB tile
      int row = y >> 6;                            // 64B per row (32 bf16)
      int ke  = (y >> 4) & 3;                      // 16B chunk within row
      gload16(A  + (size_t)(bm + row) * Ki + kk + ke * 8, (char*)As + (w * 2 + i) * 1024);
      gload16(Bw + (size_t)(bn + row) * Ki + kk + ke * 8, (char*)Bs + (w * 2 + i) * 1024);
    }
    __syncthreads();
    s16x8 af[4], bf[4];
    #pragma unroll
    for (int i = 0; i < 4; i++){
      af[i] = *(const s16x8*)(As + (size_t)(wm * 64 + i * 16 + (lane & 15)) * BKG + (lane >> 4) * 8);
      bf[i] = *(const s16x8*)(Bs + (size_t)(wn * 64 + i * 16 + (lane & 15)) * BKG + (lane >> 4) * 8);
    }
    #pragma unroll
    for (int i = 0; i < 4; i++)
      #pragma unroll
      for (int j = 0; j < 4; j++)
        acc[i][j] = mfma16(af[i], bf[j], acc[i][j]);
    __syncthreads();
  }

  // epilogue: D layout col = lane&15, row = (lane>>4)*4 + r  (m91-verified)
  #pragma unroll
  for (int j = 0; j < 4; j++){
    int n = bn + wn * 64 + j * 16 + (lane & 15);
    float bv = bias[n];
    #pragma unroll
    for (int i = 0; i < 4; i++){
      int m0 = bm + wm * 64 + i * 16 + (lane >> 4) * 4;
      #pragma unroll
      for (int r = 0; r < 4; r++){
        float v = acc[i][j][r] + bv;
        if constexpr (sizeof(OT) == 4)
          C[(size_t)(m0 + r) * Ni + n] = v;
        else
          C[(size_t)(m0 + r) * Ni + n] = f2bf(v);
      }
    }
  }
}

// ---------------- V transpose: V[b][t][h*64+dk] -> Vt[(b*H+h)][dk][t] ----------------
__global__ __launch_bounds__(256) void transpose_v(const u16t* __restrict__ V,
                                                   u16t* __restrict__ Vt){
  __shared__ u16t tle[64][65];
  const int bh = blockIdx.y, b = bh >> 4, h = bh & 15;
  const int t0 = blockIdx.x * 64;
  const u16t* vp = V + (size_t)(b * T_ + t0) * D_ + h * DK_;
  #pragma unroll
  for (int i = 0; i < 16; i++){
    int idx = threadIdx.x + i * 256;
    int tr = idx >> 6, dk = idx & 63;
    tle[tr][dk] = vp[(size_t)tr * D_ + dk];
  }
  __syncthreads();
  u16t* op = Vt + (size_t)bh * DK_ * T_ + t0;
  #pragma unroll
  for (int i = 0; i < 16; i++){
    int idx = threadIdx.x + i * 256;
    int dk = idx >> 6, tr = idx & 63;
    op[(size_t)dk * T_ + tr] = tle[tr][dk];
  }
}

// ---------------- flash attention (LDS-staged K/V, double-buffered) ----------------
// grid (T/128, B*H), 512 threads = 8 waves, 16 q-rows each.
// K,V tiles (64 keys) staged via global_load_lds with chunk-XOR swizzle:
// linear LDS dest + inverse-swizzled global source + swizzled ds_read (rule #21).
#define KVB 64

__global__ __launch_bounds__(512) void attn(const u16t* __restrict__ Q,
                                            const u16t* __restrict__ K,
                                            const u16t* __restrict__ Vt,
                                            const int* __restrict__ mask,
                                            u16t* __restrict__ X){
  __shared__ u16t Ks[2][KVB * 64];   // [buf][row*64 + col], 128B rows, 8KB
  __shared__ u16t Vs[2][KVB * 64];   // rows = dk, cols = 64 keys

  const int tid = threadIdx.x;
  const int lane = tid & 63;
  const int w = tid >> 6;
  const int q16 = lane & 15, g = lane >> 4;
  const int bh = blockIdx.y, b = bh >> 4, h = bh & 15;
  const int tq = blockIdx.x * 128 + w * 16 + q16;

  const u16t* qp = Q + (size_t)(b * T_ + tq) * D_ + h * DK_ + g * 8;
  s16x8 qf0 = *(const s16x8*)(qp);
  s16x8 qf1 = *(const s16x8*)(qp + 32);

  const f32x4 z4 = {0.f, 0.f, 0.f, 0.f};
  f32x4 acc[4];
  #pragma unroll
  for (int d = 0; d < 4; d++) acc[d] = z4;
  float mrun = -1e30f, lsum = 0.f;

  const u16t* kbase = K + (size_t)b * T_ * D_ + h * DK_;
  const u16t* vbase = Vt + (size_t)bh * DK_ * T_;
  const int* mb = mask + (size_t)b * T_;

  // staging geometry: thread -> (row = tid>>3, 16B chunk tid&7), source chunk
  // pre-swizzled so that LDS holds chunk (c ^ (row&7)) at linear slot c.
  const int srow = tid >> 3;                       // 0..63
  const int sc   = (tid & 7) ^ (srow & 7);         // global 16B chunk to fetch
  const u16t* ksrc = kbase + (size_t)srow * D_ + sc * 8;   // + t*KVB*D_ per tile
  const u16t* vsrc = vbase + (size_t)srow * T_ + sc * 8;   // + t*KVB per tile

  // prologue: stage tile 0 into buf 0
  gload16(ksrc, (u16t*)Ks[0] + w * 512);
  gload16(vsrc, (u16t*)Vs[0] + w * 512);
  __syncthreads();

  const int NT = T_ / KVB;   // 32
  for (int t = 0; t < NT; t++){
    const int buf = t & 1;
    if (t + 1 < NT){
      gload16(ksrc + (size_t)(t + 1) * KVB * D_, (u16t*)Ks[buf ^ 1] + w * 512);
      gload16(vsrc + (size_t)(t + 1) * KVB,      (u16t*)Vs[buf ^ 1] + w * 512);
    }
    const u16t* Kb = Ks[buf];
    const u16t* Vb = Vs[buf];

    #pragma unroll
    for (int s = 0; s < 2; s++){
      const int kt = t * KVB + s * 32;
      // K frags from LDS (swizzled chunks): rows s*32+q16, s*32+16+q16
      const int r0 = s * 32 + q16, r1 = r0 + 16;
      s16x8 k00 = *(const s16x8*)(Kb + r0 * 64 + (((g    ) ^ (r0 & 7)) << 3));
      s16x8 k01 = *(const s16x8*)(Kb + r0 * 64 + (((g + 4) ^ (r0 & 7)) << 3));
      s16x8 k10 = *(const s16x8*)(Kb + r1 * 64 + (((g    ) ^ (r1 & 7)) << 3));
      s16x8 k11 = *(const s16x8*)(Kb + r1 * 64 + (((g + 4) ^ (r1 & 7)) << 3));
      f32x4 s0 = z4, s1 = z4;
      s0 = mfma16(k00, qf0, s0); s0 = mfma16(k01, qf1, s0);
      s1 = mfma16(k10, qf0, s1); s1 = mfma16(k11, qf1, s1);

      // mask (int32 per key) + scale
      int4 mm0 = *(const int4*)(mb + kt + g * 4);
      int4 mm1 = *(const int4*)(mb + kt + 16 + g * 4);
      int mA[4] = {mm0.x, mm0.y, mm0.z, mm0.w};
      int mBv[4] = {mm1.x, mm1.y, mm1.z, mm1.w};
      float sv0[4], sv1[4];
      #pragma unroll
      for (int r = 0; r < 4; r++){
        sv0[r] = mA[r]  ? -3e38f : s0[r] * 0.125f;
        sv1[r] = mBv[r] ? -3e38f : s1[r] * 0.125f;
      }
      // online softmax per q-column
      float mx = sv0[0];
      #pragma unroll
      for (int r = 1; r < 4; r++) mx = fmaxf(mx, sv0[r]);
      #pragma unroll
      for (int r = 0; r < 4; r++) mx = fmaxf(mx, sv1[r]);
      mx = fmaxf(mx, __shfl_xor(mx, 16, 64));
      mx = fmaxf(mx, __shfl_xor(mx, 32, 64));
      float mnew = fmaxf(mrun, mx);
      float fsc = __expf(mrun - mnew);
      float p0[4], p1[4], ts = 0.f;
      #pragma unroll
      for (int r = 0; r < 4; r++){
        p0[r] = __expf(sv0[r] - mnew);
        p1[r] = __expf(sv1[r] - mnew);
        ts += p0[r] + p1[r];
      }
      ts += __shfl_xor(ts, 16, 64);
      ts += __shfl_xor(ts, 32, 64);
      lsum = lsum * fsc + ts;
      mrun = mnew;
      #pragma unroll
      for (int d = 0; d < 4; d++) acc[d] = acc[d] * fsc;

      // Build PV B-fragment: lane needs P^T[k=g*8+j][q], j=0..7
      u32t w0a = ((u32t)f2bf(p0[1]) << 16) | f2bf(p0[0]);
      u32t w1a = ((u32t)f2bf(p0[3]) << 16) | f2bf(p0[2]);
      u32t w0b = ((u32t)f2bf(p1[1]) << 16) | f2bf(p1[0]);
      u32t w1b = ((u32t)f2bf(p1[3]) << 16) | f2bf(p1[2]);
      int laneA = ((g & 1) << 5) | q16;
      u32t a0 = (u32t)__shfl((int)w0a, laneA, 64);
      u32t a1 = (u32t)__shfl((int)w1a, laneA, 64);
      u32t a2 = (u32t)__shfl((int)w0b, laneA, 64);
      u32t a3 = (u32t)__shfl((int)w1b, laneA, 64);
      u32t b0 = (u32t)__shfl((int)w0a, laneA + 16, 64);
      u32t b1 = (u32t)__shfl((int)w1a, laneA + 16, 64);
      u32t b2 = (u32t)__shfl((int)w0b, laneA + 16, 64);
      u32t b3 = (u32t)__shfl((int)w1b, laneA + 16, 64);
      bool hi = (g >= 2);
      union { u32t u[4]; s16x8 v; } pf;
      pf.u[0] = hi ? a2 : a0;
      pf.u[1] = hi ? a3 : a1;
      pf.u[2] = hi ? b2 : b0;
      pf.u[3] = hi ? b3 : b1;

      // PV from LDS V tile: row = d*16+q16 (dk), key chunk s*4+g, swizzled
      #pragma unroll
      for (int d = 0; d < 4; d++){
        const int vr = d * 16 + q16;
        s16x8 vf = *(const s16x8*)(Vb + vr * 64 + (((s * 4 + g) ^ (vr & 7)) << 3));
        acc[d] = mfma16(vf, pf.v, acc[d]);
      }
    }
    __syncthreads();   // drains prefetch (vmcnt 0) + swap safety
  }

  float inv = (lsum > 0.f) ? 1.0f / lsum : 0.f;
  u16t* xp = X + (size_t)(b * T_ + tq) * D_ + h * DK_ + g * 4;
  #pragma unroll
  for (int d = 0; d < 4; d++){
    u32t o0 = ((u32t)f2bf(acc[d][1] * inv) << 16) | f2bf(acc[d][0] * inv);
    u32t o1 = ((u32t)f2bf(acc[d][3] * inv) << 16) | f2bf(acc[d][2] * inv);
    *(u64t*)(xp + d * 16) = ((u64t)o1 << 32) | o0;
  }
}

extern "C" void kernel_launch(void* const* d_in, const int* in_sizes, int n_in,
                              void* d_out, int out_size, void* d_ws, size_t ws_size,
                              hipStream_t stream){
  (void)in_sizes; (void)n_in; (void)out_size; (void)ws_size;
  const float* query = (const float*)d_in[0];
  const float* key   = (const float*)d_in[1];
  const float* value = (const float*)d_in[2];
  const int*   mask  = (const int*)d_in[3];
  const float* wq = (const float*)d_in[4];
  const float* bq = (const float*)d_in[5];
  const float* wk = (const float*)d_in[6];
  const float* bk = (const float*)d_in[7];
  const float* wv = (const float*)d_in[8];
  const float* bv = (const float*)d_in[9];
  const float* wo = (const float*)d_in[10];
  const float* bo = (const float*)d_in[11];

  const size_t A = (size_t)M_ * D_;     // 8388608 elements
  const size_t W = (size_t)D_ * D_;     // 1048576
  u16t* ws  = (u16t*)d_ws;
  u16t* qb  = ws;
  u16t* kb  = ws + A;
  u16t* vb  = ws + 2 * A;
  u16t* Qm  = ws + 3 * A;
  u16t* Km  = ws + 4 * A;
  u16t* Vm  = ws + 5 * A;
  u16t* wqb = ws + 6 * A;
  u16t* wkb = wqb + W;
  u16t* wvb = wqb + 2 * W;
  u16t* wob = wqb + 3 * W;
  u16t* Vt  = qb;   // reuse: qb consumed by Q-proj before transpose runs
  u16t* Xm  = kb;   // reuse: kb consumed by K-proj before attention runs

  int nA4 = (int)(A / 4), nW4 = (int)(W / 4);
  cvt_bf16<<<nA4 / 256, 256, 0, stream>>>(query, qb, nA4);
  cvt_bf16<<<nA4 / 256, 256, 0, stream>>>(key,   kb, nA4);
  cvt_bf16<<<nA4 / 256, 256, 0, stream>>>(value, vb, nA4);
  cvt_bf16<<<nW4 / 256, 256, 0, stream>>>(wq, wqb, nW4);
  cvt_bf16<<<nW4 / 256, 256, 0, stream>>>(wk, wkb, nW4);
  cvt_bf16<<<nW4 / 256, 256, 0, stream>>>(wv, wvb, nW4);
  cvt_bf16<<<nW4 / 256, 256, 0, stream>>>(wo, wob, nW4);

  dim3 gg(M_ / BM, D_ / BN);
  gemm_bt<u16t><<<gg, 256, 0, stream>>>(qb, wqb, bq, Qm, M_, D_, D_);
  gemm_bt<u16t><<<gg, 256, 0, stream>>>(kb, wkb, bk, Km, M_, D_, D_);
  gemm_bt<u16t><<<gg, 256, 0, stream>>>(vb, wvb, bv, Vm, M_, D_, D_);

  transpose_v<<<dim3(T_ / 64, B_ * H_), 256, 0, stream>>>(Vm, Vt);

  attn<<<dim3(T_ / 128, B_ * H_), 512, 0, stream>>>(Qm, Km, Vt, mask, Xm);

  // final projection writes fp32 (reference output dtype is float32)
  gemm_bt<float><<<gg, 256, 0, stream>>>(Xm, wob, bo, (float*)d_out, M_, D_, D_);
}

// Round 6
// 421.287 us; speedup vs baseline: 1.8439x; 1.0870x over previous
//
#include <hip/hip_runtime.h>

#define B_ 4
#define T_ 2048
#define D_ 1024
#define H_ 16
#define DK_ 64
#define M_ (B_*T_)   // 8192

typedef __attribute__((ext_vector_type(4))) float f32x4;
typedef __attribute__((ext_vector_type(8))) short s16x8;
typedef unsigned short u16t;
typedef unsigned int   u32t;
typedef unsigned long long u64t;

__device__ __forceinline__ u16t f2bf(float x){
  u32t u = __float_as_uint(x);
  return (u16t)((u + 0x7FFFu + ((u >> 16) & 1u)) >> 16);
}

// packed f32x2 -> bf16x2 (RNE), gfx950 HW op (T12 recipe; no builtin exists)
__device__ __forceinline__ u32t cvt_pk_bf16(float lo, float hi){
  u32t r;
  asm("v_cvt_pk_bf16_f32 %0, %1, %2" : "=v"(r) : "v"(lo), "v"(hi));
  return r;
}

__device__ __forceinline__ f32x4 mfma16(s16x8 a, s16x8 b, f32x4 c){
  return __builtin_amdgcn_mfma_f32_16x16x32_bf16(a, b, c, 0, 0, 0);
}

// async global->LDS, 16B per lane; LDS dest = wave-uniform base + lane*16
__device__ __forceinline__ void gload16(const void* g, void* l){
  __builtin_amdgcn_global_load_lds(
      (const __attribute__((address_space(1))) u32t*)g,
      (__attribute__((address_space(3))) u32t*)l, 16, 0, 0);
}

__device__ __forceinline__ void cvt_body(const float* __restrict__ src,
                                         u16t* __restrict__ dst, int i){
  float4 v = ((const float4*)src)[i];
  u64t o = (u64t)f2bf(v.x) | ((u64t)f2bf(v.y) << 16)
         | ((u64t)f2bf(v.z) << 32) | ((u64t)f2bf(v.w) << 48);
  ((u64t*)dst)[i] = o;
}

// ---------------- fp32 -> bf16 converts, merged ----------------
// inputs: query/key/value -> qb/kb/vb. 8192 blocks per segment.
__global__ __launch_bounds__(256) void cvt_inputs(const float* __restrict__ q,
                                                  const float* __restrict__ k,
                                                  const float* __restrict__ v,
                                                  u16t* __restrict__ dst){
  int blk = blockIdx.x;
  const float* src;
  u16t* d;
  const int SEG = (M_ * D_ / 4) / 256;   // 8192 blocks
  if (blk < SEG){ src = q; d = dst; }
  else if (blk < 2*SEG){ src = k; d = dst + (size_t)M_*D_; blk -= SEG; }
  else { src = v; d = dst + 2*(size_t)M_*D_; blk -= 2*SEG; }
  cvt_body(src, d, blk * 256 + threadIdx.x);
}

// weights wq/wk/wv/wo -> wqb.. (contiguous), + mask(int32) -> float bias.
// 1024 blocks per weight (4096), then 32 blocks for mask.
__global__ __launch_bounds__(256) void cvt_weights(const float* __restrict__ wq,
                                                   const float* __restrict__ wk,
                                                   const float* __restrict__ wv,
                                                   const float* __restrict__ wo,
                                                   u16t* __restrict__ wdst,
                                                   const int* __restrict__ mask,
                                                   float* __restrict__ maskf){
  int blk = blockIdx.x;
  const int SEG = (D_ * D_ / 4) / 256;   // 1024
  if (blk < 4*SEG){
    const float* src = (blk < SEG) ? wq : (blk < 2*SEG) ? wk : (blk < 3*SEG) ? wv : wo;
    u16t* d = wdst + (size_t)(blk / SEG) * D_ * D_;
    cvt_body(src, d, (blk % SEG) * 256 + threadIdx.x);
  } else {
    int i = (blk - 4*SEG) * 256 + threadIdx.x;   // 0..8191
    maskf[i] = mask[i] ? -3e38f : 0.f;
  }
}

// ---------------- GEMM: C[m][n] = sum_k A[m][k]*Bw[n][k] + bias[n] ----------------
// 128x128 tile, BK=32, 4 waves (2x2), 16x16x32 bf16 MFMA, global_load_lds w16.
#define BM 128
#define BN 128
#define BKG 32

template<typename OT>
__device__ __forceinline__ void gemm_core(const u16t* __restrict__ A,
                                          const u16t* __restrict__ Bw,
                                          const float* __restrict__ bias,
                                          OT* __restrict__ C,
                                          int Ni, int Ki,
                                          u16t* As, u16t* Bs){
  const int tid = threadIdx.x, lane = tid & 63, w = tid >> 6;
  const int wm = w >> 1, wn = w & 1;
  const int bm = blockIdx.x * BM, bn = blockIdx.y * BN;

  f32x4 acc[4][4];
  const f32x4 z4 = {0.f, 0.f, 0.f, 0.f};
  #pragma unroll
  for (int i = 0; i < 4; i++)
    #pragma unroll
    for (int j = 0; j < 4; j++) acc[i][j] = z4;

  for (int kk = 0; kk < Ki; kk += BKG){
    #pragma unroll
    for (int i = 0; i < 2; i++){
      int y   = (w * 2 + i) * 1024 + lane * 16;   // linear byte in 8KB tile
      int row = y >> 6;                            // 64B per row (32 bf16)
      int ke  = (y >> 4) & 3;                      // 16B chunk within row
      gload16(A  + (size_t)(bm + row) * Ki + kk + ke * 8, (char*)As + (w * 2 + i) * 1024);
      gload16(Bw + (size_t)(bn + row) * Ki + kk + ke * 8, (char*)Bs + (w * 2 + i) * 1024);
    }
    __syncthreads();
    s16x8 af[4], bf[4];
    #pragma unroll
    for (int i = 0; i < 4; i++){
      af[i] = *(const s16x8*)(As + (size_t)(wm * 64 + i * 16 + (lane & 15)) * BKG + (lane >> 4) * 8);
      bf[i] = *(const s16x8*)(Bs + (size_t)(wn * 64 + i * 16 + (lane & 15)) * BKG + (lane >> 4) * 8);
    }
    #pragma unroll
    for (int i = 0; i < 4; i++)
      #pragma unroll
      for (int j = 0; j < 4; j++)
        acc[i][j] = mfma16(af[i], bf[j], acc[i][j]);
    __syncthreads();
  }

  // epilogue: D layout col = lane&15, row = (lane>>4)*4 + r  (m91-verified)
  #pragma unroll
  for (int j = 0; j < 4; j++){
    int n = bn + wn * 64 + j * 16 + (lane & 15);
    float bv = bias[n];
    #pragma unroll
    for (int i = 0; i < 4; i++){
      int m0 = bm + wm * 64 + i * 16 + (lane >> 4) * 4;
      #pragma unroll
      for (int r = 0; r < 4; r++){
        float v = acc[i][j][r] + bv;
        if constexpr (sizeof(OT) == 4)
          C[(size_t)(m0 + r) * Ni + n] = v;
        else
          C[(size_t)(m0 + r) * Ni + n] = f2bf(v);
      }
    }
  }
}

// Q/K/V projections fused: blockIdx.z selects input/weight/bias/output.
// in/out/weights are contiguous per-z in workspace.
__global__ __launch_bounds__(256, 2) void gemm_qkv(const u16t* __restrict__ in0,
                                                   const u16t* __restrict__ w0,
                                                   const float* __restrict__ b0,
                                                   const float* __restrict__ b1,
                                                   const float* __restrict__ b2,
                                                   u16t* __restrict__ out0){
  __shared__ u16t As[BM * BKG];
  __shared__ u16t Bs[BN * BKG];
  const int z = blockIdx.z;
  const float* bias = (z == 0) ? b0 : (z == 1) ? b1 : b2;
  gemm_core<u16t>(in0 + (size_t)z * M_ * D_, w0 + (size_t)z * D_ * D_, bias,
                  out0 + (size_t)z * M_ * D_, D_, D_, As, Bs);
}

__global__ __launch_bounds__(256, 2) void gemm_out(const u16t* __restrict__ A,
                                                   const u16t* __restrict__ Bw,
                                                   const float* __restrict__ bias,
                                                   float* __restrict__ C){
  __shared__ u16t As[BM * BKG];
  __shared__ u16t Bs[BN * BKG];
  gemm_core<float>(A, Bw, bias, C, D_, D_, As, Bs);
}

// ---------------- V transpose: V[b][t][h*64+dk] -> Vt[(b*H+h)][dk][t] ----------------
__global__ __launch_bounds__(256) void transpose_v(const u16t* __restrict__ V,
                                                   u16t* __restrict__ Vt){
  __shared__ u16t tle[64][65];
  const int bh = blockIdx.y, b = bh >> 4, h = bh & 15;
  const int t0 = blockIdx.x * 64;
  const u16t* vp = V + (size_t)(b * T_ + t0) * D_ + h * DK_;
  #pragma unroll
  for (int i = 0; i < 16; i++){
    int idx = threadIdx.x + i * 256;
    int tr = idx >> 6, dk = idx & 63;
    tle[tr][dk] = vp[(size_t)tr * D_ + dk];
  }
  __syncthreads();
  u16t* op = Vt + (size_t)bh * DK_ * T_ + t0;
  #pragma unroll
  for (int i = 0; i < 16; i++){
    int idx = threadIdx.x + i * 256;
    int dk = idx >> 6, tr = idx & 63;
    op[(size_t)dk * T_ + tr] = tle[tr][dk];
  }
}

// ---------------- flash attention (LDS-staged K/V, double-buffered) ----------------
// grid (T/128, B*H), 512 threads = 8 waves, 16 q-rows each.
// VALU diet vs r5: cvt_pk packing, defer-max (THR=8), mask as float-bias FMA.
#define KVB 64

__global__ __launch_bounds__(512) void attn(const u16t* __restrict__ Q,
                                            const u16t* __restrict__ K,
                                            const u16t* __restrict__ Vt,
                                            const float* __restrict__ maskf,
                                            u16t* __restrict__ X){
  __shared__ u16t Ks[2][KVB * 64];   // [buf][row*64 + col], 128B rows, 8KB
  __shared__ u16t Vs[2][KVB * 64];   // rows = dk, cols = 64 keys

  const int tid = threadIdx.x;
  const int lane = tid & 63;
  const int w = tid >> 6;
  const int q16 = lane & 15, g = lane >> 4;
  const int bh = blockIdx.y, b = bh >> 4, h = bh & 15;
  const int tq = blockIdx.x * 128 + w * 16 + q16;

  const u16t* qp = Q + (size_t)(b * T_ + tq) * D_ + h * DK_ + g * 8;
  s16x8 qf0 = *(const s16x8*)(qp);
  s16x8 qf1 = *(const s16x8*)(qp + 32);

  const f32x4 z4 = {0.f, 0.f, 0.f, 0.f};
  f32x4 acc[4];
  #pragma unroll
  for (int d = 0; d < 4; d++) acc[d] = z4;
  float mrun = -1e30f, lsum = 0.f;

  const u16t* kbase = K + (size_t)b * T_ * D_ + h * DK_;
  const u16t* vbase = Vt + (size_t)bh * DK_ * T_;
  const float* mb = maskf + (size_t)b * T_;

  // staging geometry: thread -> (row = tid>>3, 16B chunk tid&7), source chunk
  // pre-swizzled so that LDS holds chunk (c ^ (row&7)) at linear slot c.
  const int srow = tid >> 3;                       // 0..63
  const int sc   = (tid & 7) ^ (srow & 7);         // global 16B chunk to fetch
  const u16t* ksrc = kbase + (size_t)srow * D_ + sc * 8;   // + t*KVB*D_ per tile
  const u16t* vsrc = vbase + (size_t)srow * T_ + sc * 8;   // + t*KVB per tile

  // prologue: stage tile 0 into buf 0
  gload16(ksrc, (u16t*)Ks[0] + w * 512);
  gload16(vsrc, (u16t*)Vs[0] + w * 512);
  __syncthreads();

  const int NT = T_ / KVB;   // 32
  for (int t = 0; t < NT; t++){
    const int buf = t & 1;
    if (t + 1 < NT){
      gload16(ksrc + (size_t)(t + 1) * KVB * D_, (u16t*)Ks[buf ^ 1] + w * 512);
      gload16(vsrc + (size_t)(t + 1) * KVB,      (u16t*)Vs[buf ^ 1] + w * 512);
    }
    const u16t* Kb = Ks[buf];
    const u16t* Vb = Vs[buf];

    #pragma unroll
    for (int s = 0; s < 2; s++){
      const int kt = t * KVB + s * 32;
      // K frags from LDS (swizzled chunks): rows s*32+q16, s*32+16+q16
      const int r0 = s * 32 + q16, r1 = r0 + 16;
      s16x8 k00 = *(const s16x8*)(Kb + r0 * 64 + (((g    ) ^ (r0 & 7)) << 3));
      s16x8 k01 = *(const s16x8*)(Kb + r0 * 64 + (((g + 4) ^ (r0 & 7)) << 3));
      s16x8 k10 = *(const s16x8*)(Kb + r1 * 64 + (((g    ) ^ (r1 & 7)) << 3));
      s16x8 k11 = *(const s16x8*)(Kb + r1 * 64 + (((g + 4) ^ (r1 & 7)) << 3));
      f32x4 s0 = z4, s1 = z4;
      s0 = mfma16(k00, qf0, s0); s0 = mfma16(k01, qf1, s0);
      s1 = mfma16(k10, qf0, s1); s1 = mfma16(k11, qf1, s1);

      // mask as additive float bias (0 / -3e38): sv = s*0.125 + bias
      float4 mb0 = *(const float4*)(mb + kt + g * 4);
      float4 mb1 = *(const float4*)(mb + kt + 16 + g * 4);
      float bA[4] = {mb0.x, mb0.y, mb0.z, mb0.w};
      float bB[4] = {mb1.x, mb1.y, mb1.z, mb1.w};
      float sv0[4], sv1[4];
      #pragma unroll
      for (int r = 0; r < 4; r++){
        sv0[r] = fmaf(s0[r], 0.125f, bA[r]);
        sv1[r] = fmaf(s1[r], 0.125f, bB[r]);
      }
      // tile max per q-column (uniform across g after 2 shfl_xor)
      float mx = fmaxf(sv0[0], sv0[1]);
      mx = fmaxf(mx, fmaxf(sv0[2], sv0[3]));
      mx = fmaxf(mx, fmaxf(sv1[0], sv1[1]));
      mx = fmaxf(mx, fmaxf(sv1[2], sv1[3]));
      mx = fmaxf(mx, __shfl_xor(mx, 16, 64));
      mx = fmaxf(mx, __shfl_xor(mx, 32, 64));

      // defer-max (T13): rescale only when some column grew past mrun+8
      if (__any(mx > mrun + 8.0f)){
        float mnew = fmaxf(mrun, mx);
        float fsc = __expf(mrun - mnew);
        lsum *= fsc;
        #pragma unroll
        for (int d = 0; d < 4; d++) acc[d] = acc[d] * fsc;
        mrun = mnew;
      }

      float p0[4], p1[4], ts = 0.f;
      #pragma unroll
      for (int r = 0; r < 4; r++){
        p0[r] = __expf(sv0[r] - mrun);
        p1[r] = __expf(sv1[r] - mrun);
        ts += p0[r] + p1[r];
      }
      ts += __shfl_xor(ts, 16, 64);
      ts += __shfl_xor(ts, 32, 64);
      lsum += ts;

      // pack P to bf16 pairs (HW packed cvt), then redistribute:
      // lane needs P^T[k=g*8+j][q], j=0..7
      u32t w0a = cvt_pk_bf16(p0[0], p0[1]);
      u32t w1a = cvt_pk_bf16(p0[2], p0[3]);
      u32t w0b = cvt_pk_bf16(p1[0], p1[1]);
      u32t w1b = cvt_pk_bf16(p1[2], p1[3]);
      int laneA = ((g & 1) << 5) | q16;
      u32t a0 = (u32t)__shfl((int)w0a, laneA, 64);
      u32t a1 = (u32t)__shfl((int)w1a, laneA, 64);
      u32t a2 = (u32t)__shfl((int)w0b, laneA, 64);
      u32t a3 = (u32t)__shfl((int)w1b, laneA, 64);
      u32t b0 = (u32t)__shfl((int)w0a, laneA + 16, 64);
      u32t b1 = (u32t)__shfl((int)w1a, laneA + 16, 64);
      u32t b2 = (u32t)__shfl((int)w0b, laneA + 16, 64);
      u32t b3 = (u32t)__shfl((int)w1b, laneA + 16, 64);
      bool hi = (g >= 2);
      union { u32t u[4]; s16x8 v; } pf;
      pf.u[0] = hi ? a2 : a0;
      pf.u[1] = hi ? a3 : a1;
      pf.u[2] = hi ? b2 : b0;
      pf.u[3] = hi ? b3 : b1;

      // PV from LDS V tile: row = d*16+q16 (dk), key chunk s*4+g, swizzled
      #pragma unroll
      for (int d = 0; d < 4; d++){
        const int vr = d * 16 + q16;
        s16x8 vf = *(const s16x8*)(Vb + vr * 64 + (((s * 4 + g) ^ (vr & 7)) << 3));
        acc[d] = mfma16(vf, pf.v, acc[d]);
      }
    }
    __syncthreads();   // drains prefetch (vmcnt 0) + swap safety
  }

  float inv = (lsum > 0.f) ? 1.0f / lsum : 0.f;
  u16t* xp = X + (size_t)(b * T_ + tq) * D_ + h * DK_ + g * 4;
  #pragma unroll
  for (int d = 0; d < 4; d++){
    u32t o0 = ((u32t)f2bf(acc[d][1] * inv) << 16) | f2bf(acc[d][0] * inv);
    u32t o1 = ((u32t)f2bf(acc[d][3] * inv) << 16) | f2bf(acc[d][2] * inv);
    *(u64t*)(xp + d * 16) = ((u64t)o1 << 32) | o0;
  }
}

extern "C" void kernel_launch(void* const* d_in, const int* in_sizes, int n_in,
                              void* d_out, int out_size, void* d_ws, size_t ws_size,
                              hipStream_t stream){
  (void)in_sizes; (void)n_in; (void)out_size; (void)ws_size;
  const float* query = (const float*)d_in[0];
  const float* key   = (const float*)d_in[1];
  const float* value = (const float*)d_in[2];
  const int*   mask  = (const int*)d_in[3];
  const float* wq = (const float*)d_in[4];
  const float* bq = (const float*)d_in[5];
  const float* wk = (const float*)d_in[6];
  const float* bk = (const float*)d_in[7];
  const float* wv = (const float*)d_in[8];
  const float* bv = (const float*)d_in[9];
  const float* wo = (const float*)d_in[10];
  const float* bo = (const float*)d_in[11];

  const size_t A = (size_t)M_ * D_;     // 8388608 elements
  const size_t W = (size_t)D_ * D_;     // 1048576
  u16t* ws  = (u16t*)d_ws;
  u16t* qb  = ws;                 // qb,kb,vb contiguous (cvt_inputs, gemm_qkv)
  u16t* Qm  = ws + 3 * A;         // Qm,Km,Vm contiguous (gemm_qkv outputs)
  u16t* Km  = ws + 4 * A;
  u16t* Vm  = ws + 5 * A;
  u16t* wqb = ws + 6 * A;         // wqb,wkb,wvb,wob contiguous
  u16t* wob = wqb + 3 * W;
  float* maskf = (float*)(wqb + 4 * W);   // 8192 floats
  u16t* Vt  = qb;                 // reuse: qb consumed by QKV-proj before transpose
  u16t* Xm  = qb + A;             // reuse: kb slot

  const int SEGA = (int)(A / 4) / 256;   // 8192 blocks per input
  const int SEGW = (int)(W / 4) / 256;   // 1024 blocks per weight
  cvt_inputs<<<3 * SEGA, 256, 0, stream>>>(query, key, value, qb);
  cvt_weights<<<4 * SEGW + 32, 256, 0, stream>>>(wq, wk, wv, wo, wqb, mask, maskf);

  gemm_qkv<<<dim3(M_ / BM, D_ / BN, 3), 256, 0, stream>>>(qb, wqb, bq, bk, bv, Qm);

  transpose_v<<<dim3(T_ / 64, B_ * H_), 256, 0, stream>>>(Vm, Vt);

  attn<<<dim3(T_ / 128, B_ * H_), 512, 0, stream>>>(Qm, Km, Vt, maskf, Xm);

  // final projection writes fp32 (reference output dtype is float32)
  gemm_out<<<dim3(M_ / BM, D_ / BN), 256, 0, stream>>>(Xm, wob, bo, (float*)d_out);
}

// Round 7
// 388.375 us; speedup vs baseline: 2.0002x; 1.0847x over previous
//
#include <hip/hip_runtime.h>

#define B_ 4
#define T_ 2048
#define D_ 1024
#define H_ 16
#define DK_ 64
#define M_ (B_*T_)   // 8192

typedef __attribute__((ext_vector_type(4))) float f32x4;
typedef __attribute__((ext_vector_type(8))) short s16x8;
typedef unsigned short u16t;
typedef unsigned int   u32t;
typedef unsigned long long u64t;

__device__ __forceinline__ u16t f2bf(float x){
  u32t u = __float_as_uint(x);
  return (u16t)((u + 0x7FFFu + ((u >> 16) & 1u)) >> 16);
}

// packed f32x2 -> bf16x2 (RNE), gfx950 HW op (T12 recipe; no builtin exists)
__device__ __forceinline__ u32t cvt_pk_bf16(float lo, float hi){
  u32t r;
  asm("v_cvt_pk_bf16_f32 %0, %1, %2" : "=v"(r) : "v"(lo), "v"(hi));
  return r;
}

__device__ __forceinline__ f32x4 mfma16(s16x8 a, s16x8 b, f32x4 c){
  return __builtin_amdgcn_mfma_f32_16x16x32_bf16(a, b, c, 0, 0, 0);
}

// async global->LDS, 16B per lane; LDS dest = wave-uniform base + lane*16
__device__ __forceinline__ void gload16(const void* g, void* l){
  __builtin_amdgcn_global_load_lds(
      (const __attribute__((address_space(1))) u32t*)g,
      (__attribute__((address_space(3))) u32t*)l, 16, 0, 0);
}

__device__ __forceinline__ void cvt_body(const float* __restrict__ src,
                                         u16t* __restrict__ dst, int i){
  float4 v = ((const float4*)src)[i];
  u64t o = (u64t)f2bf(v.x) | ((u64t)f2bf(v.y) << 16)
         | ((u64t)f2bf(v.z) << 32) | ((u64t)f2bf(v.w) << 48);
  ((u64t*)dst)[i] = o;
}

// ---------------- fp32 -> bf16 converts, merged ----------------
__global__ __launch_bounds__(256) void cvt_inputs(const float* __restrict__ q,
                                                  const float* __restrict__ k,
                                                  const float* __restrict__ v,
                                                  u16t* __restrict__ dst){
  int blk = blockIdx.x;
  const float* src;
  u16t* d;
  const int SEG = (M_ * D_ / 4) / 256;   // 8192 blocks
  if (blk < SEG){ src = q; d = dst; }
  else if (blk < 2*SEG){ src = k; d = dst + (size_t)M_*D_; blk -= SEG; }
  else { src = v; d = dst + 2*(size_t)M_*D_; blk -= 2*SEG; }
  cvt_body(src, d, blk * 256 + threadIdx.x);
}

__global__ __launch_bounds__(256) void cvt_weights(const float* __restrict__ wq,
                                                   const float* __restrict__ wk,
                                                   const float* __restrict__ wv,
                                                   const float* __restrict__ wo,
                                                   u16t* __restrict__ wdst,
                                                   const int* __restrict__ mask,
                                                   float* __restrict__ maskf){
  int blk = blockIdx.x;
  const int SEG = (D_ * D_ / 4) / 256;   // 1024
  if (blk < 4*SEG){
    const float* src = (blk < SEG) ? wq : (blk < 2*SEG) ? wk : (blk < 3*SEG) ? wv : wo;
    u16t* d = wdst + (size_t)(blk / SEG) * D_ * D_;
    cvt_body(src, d, (blk % SEG) * 256 + threadIdx.x);
  } else {
    int i = (blk - 4*SEG) * 256 + threadIdx.x;   // 0..8191
    maskf[i] = mask[i] ? -3e38f : 0.f;
  }
}

// ---------------- GEMM: C[m][n] = sum_k A[m][k]*Bw[n][k] + bias[n] ----------------
#define BM 128
#define BN 128
#define BKG 32

template<typename OT>
__device__ __forceinline__ void gemm_core(const u16t* __restrict__ A,
                                          const u16t* __restrict__ Bw,
                                          const float* __restrict__ bias,
                                          OT* __restrict__ C,
                                          int Ni, int Ki,
                                          u16t* As, u16t* Bs){
  const int tid = threadIdx.x, lane = tid & 63, w = tid >> 6;
  const int wm = w >> 1, wn = w & 1;
  const int bm = blockIdx.x * BM, bn = blockIdx.y * BN;

  f32x4 acc[4][4];
  const f32x4 z4 = {0.f, 0.f, 0.f, 0.f};
  #pragma unroll
  for (int i = 0; i < 4; i++)
    #pragma unroll
    for (int j = 0; j < 4; j++) acc[i][j] = z4;

  for (int kk = 0; kk < Ki; kk += BKG){
    #pragma unroll
    for (int i = 0; i < 2; i++){
      int y   = (w * 2 + i) * 1024 + lane * 16;   // linear byte in 8KB tile
      int row = y >> 6;                            // 64B per row (32 bf16)
      int ke  = (y >> 4) & 3;                      // 16B chunk within row
      gload16(A  + (size_t)(bm + row) * Ki + kk + ke * 8, (char*)As + (w * 2 + i) * 1024);
      gload16(Bw + (size_t)(bn + row) * Ki + kk + ke * 8, (char*)Bs + (w * 2 + i) * 1024);
    }
    __syncthreads();
    s16x8 af[4], bf[4];
    #pragma unroll
    for (int i = 0; i < 4; i++){
      af[i] = *(const s16x8*)(As + (size_t)(wm * 64 + i * 16 + (lane & 15)) * BKG + (lane >> 4) * 8);
      bf[i] = *(const s16x8*)(Bs + (size_t)(wn * 64 + i * 16 + (lane & 15)) * BKG + (lane >> 4) * 8);
    }
    #pragma unroll
    for (int i = 0; i < 4; i++)
      #pragma unroll
      for (int j = 0; j < 4; j++)
        acc[i][j] = mfma16(af[i], bf[j], acc[i][j]);
    __syncthreads();
  }

  #pragma unroll
  for (int j = 0; j < 4; j++){
    int n = bn + wn * 64 + j * 16 + (lane & 15);
    float bv = bias[n];
    #pragma unroll
    for (int i = 0; i < 4; i++){
      int m0 = bm + wm * 64 + i * 16 + (lane >> 4) * 4;
      #pragma unroll
      for (int r = 0; r < 4; r++){
        float v = acc[i][j][r] + bv;
        if constexpr (sizeof(OT) == 4)
          C[(size_t)(m0 + r) * Ni + n] = v;
        else
          C[(size_t)(m0 + r) * Ni + n] = f2bf(v);
      }
    }
  }
}

__global__ __launch_bounds__(256, 2) void gemm_qkv(const u16t* __restrict__ in0,
                                                   const u16t* __restrict__ w0,
                                                   const float* __restrict__ b0,
                                                   const float* __restrict__ b1,
                                                   const float* __restrict__ b2,
                                                   u16t* __restrict__ out0){
  __shared__ u16t As[BM * BKG];
  __shared__ u16t Bs[BN * BKG];
  const int z = blockIdx.z;
  const float* bias = (z == 0) ? b0 : (z == 1) ? b1 : b2;
  gemm_core<u16t>(in0 + (size_t)z * M_ * D_, w0 + (size_t)z * D_ * D_, bias,
                  out0 + (size_t)z * M_ * D_, D_, D_, As, Bs);
}

__global__ __launch_bounds__(256, 2) void gemm_out(const u16t* __restrict__ A,
                                                   const u16t* __restrict__ Bw,
                                                   const float* __restrict__ bias,
                                                   float* __restrict__ C){
  __shared__ u16t As[BM * BKG];
  __shared__ u16t Bs[BN * BKG];
  gemm_core<float>(A, Bw, bias, C, D_, D_, As, Bs);
}

// ---------------- V transpose + PV-slot permutation ----------------
// Vt[(b*H+h)][dk][slot]: within each 32-key group, slot 8g+j holds
// key 4g+j (j<4) / 16+4g+(j-4) (j>=4). This makes the QK^T output layout
// (lane(q,g) holds keys {4g+r} u {16+4g+r}) directly usable as the PV
// B-fragment (slots {8g..8g+7}) with zero cross-lane shuffles.
__global__ __launch_bounds__(256) void transpose_v(const u16t* __restrict__ V,
                                                   u16t* __restrict__ Vt){
  __shared__ u16t tle[64][65];
  const int bh = blockIdx.y, b = bh >> 4, h = bh & 15;
  const int t0 = blockIdx.x * 64;
  const u16t* vp = V + (size_t)(b * T_ + t0) * D_ + h * DK_;
  #pragma unroll
  for (int i = 0; i < 16; i++){
    int idx = threadIdx.x + i * 256;
    int tr = idx >> 6, dk = idx & 63;
    tle[tr][dk] = vp[(size_t)tr * D_ + dk];
  }
  __syncthreads();
  u16t* op = Vt + (size_t)bh * DK_ * T_ + t0;
  #pragma unroll
  for (int i = 0; i < 16; i++){
    int idx = threadIdx.x + i * 256;
    int dk = idx >> 6, s = idx & 63;        // s = output slot within 64-key tile
    int grp = s & 32, s32 = s & 31;
    int g = s32 >> 3, j = s32 & 7;
    int k32 = (j < 4) ? (g * 4 + j) : (16 + g * 4 + (j - 4));
    op[(size_t)dk * T_ + s] = tle[grp + k32][dk];
  }
}

// ---------------- flash attention (LDS-staged K/V, double-buffered) ----------------
// grid (T/128, B*H), 512 threads = 8 waves, 16 q-rows each.
// r7: PV B-fragment built in-lane via slot-permuted Vt (no shuffles).
#define KVB 64

__global__ __launch_bounds__(512) void attn(const u16t* __restrict__ Q,
                                            const u16t* __restrict__ K,
                                            const u16t* __restrict__ Vt,
                                            const float* __restrict__ maskf,
                                            u16t* __restrict__ X){
  __shared__ u16t Ks[2][KVB * 64];   // [buf][row*64 + col], 128B rows, 8KB
  __shared__ u16t Vs[2][KVB * 64];   // rows = dk, cols = 64 key-slots

  const int tid = threadIdx.x;
  const int lane = tid & 63;
  const int w = tid >> 6;
  const int q16 = lane & 15, g = lane >> 4;
  const int bh = blockIdx.y, b = bh >> 4, h = bh & 15;
  const int tq = blockIdx.x * 128 + w * 16 + q16;

  const u16t* qp = Q + (size_t)(b * T_ + tq) * D_ + h * DK_ + g * 8;
  s16x8 qf0 = *(const s16x8*)(qp);
  s16x8 qf1 = *(const s16x8*)(qp + 32);

  const f32x4 z4 = {0.f, 0.f, 0.f, 0.f};
  f32x4 acc[4];
  #pragma unroll
  for (int d = 0; d < 4; d++) acc[d] = z4;
  float mrun = -1e30f, lsum = 0.f;

  const u16t* kbase = K + (size_t)b * T_ * D_ + h * DK_;
  const u16t* vbase = Vt + (size_t)bh * DK_ * T_;
  const float* mb = maskf + (size_t)b * T_;

  // staging: thread -> (row = tid>>3, 16B chunk tid&7); source chunk
  // pre-swizzled so LDS holds chunk (c ^ (row&7)) at linear slot c.
  const int srow = tid >> 3;                       // 0..63
  const int sc   = (tid & 7) ^ (srow & 7);         // global 16B chunk to fetch
  const u16t* ksrc = kbase + (size_t)srow * D_ + sc * 8;   // + t*KVB*D_ per tile
  const u16t* vsrc = vbase + (size_t)srow * T_ + sc * 8;   // + t*KVB per tile

  gload16(ksrc, (u16t*)Ks[0] + w * 512);
  gload16(vsrc, (u16t*)Vs[0] + w * 512);
  __syncthreads();

  const int NT = T_ / KVB;   // 32
  for (int t = 0; t < NT; t++){
    const int buf = t & 1;
    if (t + 1 < NT){
      gload16(ksrc + (size_t)(t + 1) * KVB * D_, (u16t*)Ks[buf ^ 1] + w * 512);
      gload16(vsrc + (size_t)(t + 1) * KVB,      (u16t*)Vs[buf ^ 1] + w * 512);
    }
    const u16t* Kb = Ks[buf];
    const u16t* Vb = Vs[buf];

    #pragma unroll
    for (int s = 0; s < 2; s++){
      const int kt = t * KVB + s * 32;
      // K frags from LDS (swizzled chunks): rows s*32+q16, s*32+16+q16
      const int r0 = s * 32 + q16, r1 = r0 + 16;
      s16x8 k00 = *(const s16x8*)(Kb + r0 * 64 + (((g    ) ^ (r0 & 7)) << 3));
      s16x8 k01 = *(const s16x8*)(Kb + r0 * 64 + (((g + 4) ^ (r0 & 7)) << 3));
      s16x8 k10 = *(const s16x8*)(Kb + r1 * 64 + (((g    ) ^ (r1 & 7)) << 3));
      s16x8 k11 = *(const s16x8*)(Kb + r1 * 64 + (((g + 4) ^ (r1 & 7)) << 3));
      f32x4 s0 = z4, s1 = z4;
      s0 = mfma16(k00, qf0, s0); s0 = mfma16(k01, qf1, s0);
      s1 = mfma16(k10, qf0, s1); s1 = mfma16(k11, qf1, s1);

      // mask as additive float bias (0 / -3e38): sv = s*0.125 + bias
      float4 mb0 = *(const float4*)(mb + kt + g * 4);
      float4 mb1 = *(const float4*)(mb + kt + 16 + g * 4);
      float bA[4] = {mb0.x, mb0.y, mb0.z, mb0.w};
      float bB[4] = {mb1.x, mb1.y, mb1.z, mb1.w};
      float sv0[4], sv1[4];
      #pragma unroll
      for (int r = 0; r < 4; r++){
        sv0[r] = fmaf(s0[r], 0.125f, bA[r]);
        sv1[r] = fmaf(s1[r], 0.125f, bB[r]);
      }
      // tile max per q-column
      float mx = fmaxf(sv0[0], sv0[1]);
      mx = fmaxf(mx, fmaxf(sv0[2], sv0[3]));
      mx = fmaxf(mx, fmaxf(sv1[0], sv1[1]));
      mx = fmaxf(mx, fmaxf(sv1[2], sv1[3]));
      mx = fmaxf(mx, __shfl_xor(mx, 16, 64));
      mx = fmaxf(mx, __shfl_xor(mx, 32, 64));

      // defer-max (T13): rescale only when some column grew past mrun+8
      if (__any(mx > mrun + 8.0f)){
        float mnew = fmaxf(mrun, mx);
        float fsc = __expf(mrun - mnew);
        lsum *= fsc;
        #pragma unroll
        for (int d = 0; d < 4; d++) acc[d] = acc[d] * fsc;
        mrun = mnew;
      }

      float p0[4], p1[4], ts = 0.f;
      #pragma unroll
      for (int r = 0; r < 4; r++){
        p0[r] = __expf(sv0[r] - mrun);
        p1[r] = __expf(sv1[r] - mrun);
        ts += p0[r] + p1[r];
      }
      ts += __shfl_xor(ts, 16, 64);
      ts += __shfl_xor(ts, 32, 64);
      lsum += ts;

      // PV B-fragment, fully in-lane: lane(q,g) supplies slots 8g..8g+7
      // = keys {4g+r} u {16+4g+r} (Vt column order matches, see transpose_v)
      union { u32t u[4]; s16x8 v; } pf;
      pf.u[0] = cvt_pk_bf16(p0[0], p0[1]);
      pf.u[1] = cvt_pk_bf16(p0[2], p0[3]);
      pf.u[2] = cvt_pk_bf16(p1[0], p1[1]);
      pf.u[3] = cvt_pk_bf16(p1[2], p1[3]);

      // PV from LDS V tile: row = d*16+q16 (dk), slot chunk s*4+g, swizzled
      #pragma unroll
      for (int d = 0; d < 4; d++){
        const int vr = d * 16 + q16;
        s16x8 vf = *(const s16x8*)(Vb + vr * 64 + (((s * 4 + g) ^ (vr & 7)) << 3));
        acc[d] = mfma16(vf, pf.v, acc[d]);
      }
    }
    __syncthreads();   // drains prefetch (vmcnt 0) + swap safety
  }

  float inv = (lsum > 0.f) ? 1.0f / lsum : 0.f;
  u16t* xp = X + (size_t)(b * T_ + tq) * D_ + h * DK_ + g * 4;
  #pragma unroll
  for (int d = 0; d < 4; d++){
    u32t o0 = ((u32t)f2bf(acc[d][1] * inv) << 16) | f2bf(acc[d][0] * inv);
    u32t o1 = ((u32t)f2bf(acc[d][3] * inv) << 16) | f2bf(acc[d][2] * inv);
    *(u64t*)(xp + d * 16) = ((u64t)o1 << 32) | o0;
  }
}

extern "C" void kernel_launch(void* const* d_in, const int* in_sizes, int n_in,
                              void* d_out, int out_size, void* d_ws, size_t ws_size,
                              hipStream_t stream){
  (void)in_sizes; (void)n_in; (void)out_size; (void)ws_size;
  const float* query = (const float*)d_in[0];
  const float* key   = (const float*)d_in[1];
  const float* value = (const float*)d_in[2];
  const int*   mask  = (const int*)d_in[3];
  const float* wq = (const float*)d_in[4];
  const float* bq = (const float*)d_in[5];
  const float* wk = (const float*)d_in[6];
  const float* bk = (const float*)d_in[7];
  const float* wv = (const float*)d_in[8];
  const float* bv = (const float*)d_in[9];
  const float* wo = (const float*)d_in[10];
  const float* bo = (const float*)d_in[11];

  const size_t A = (size_t)M_ * D_;     // 8388608 elements
  const size_t W = (size_t)D_ * D_;     // 1048576
  u16t* ws  = (u16t*)d_ws;
  u16t* qb  = ws;                 // qb,kb,vb contiguous (cvt_inputs, gemm_qkv)
  u16t* Qm  = ws + 3 * A;         // Qm,Km,Vm contiguous (gemm_qkv outputs)
  u16t* Km  = ws + 4 * A;
  u16t* Vm  = ws + 5 * A;
  u16t* wqb = ws + 6 * A;         // wqb,wkb,wvb,wob contiguous
  u16t* wob = wqb + 3 * W;
  float* maskf = (float*)(wqb + 4 * W);   // 8192 floats
  u16t* Vt  = qb;                 // reuse: qb consumed by QKV-proj before transpose
  u16t* Xm  = qb + A;             // reuse: kb slot

  const int SEGA = (int)(A / 4) / 256;   // 8192 blocks per input
  const int SEGW = (int)(W / 4) / 256;   // 1024 blocks per weight
  cvt_inputs<<<3 * SEGA, 256, 0, stream>>>(query, key, value, qb);
  cvt_weights<<<4 * SEGW + 32, 256, 0, stream>>>(wq, wk, wv, wo, wqb, mask, maskf);

  gemm_qkv<<<dim3(M_ / BM, D_ / BN, 3), 256, 0, stream>>>(qb, wqb, bq, bk, bv, Qm);

  transpose_v<<<dim3(T_ / 64, B_ * H_), 256, 0, stream>>>(Vm, Vt);

  attn<<<dim3(T_ / 128, B_ * H_), 512, 0, stream>>>(Qm, Km, Vt, maskf, Xm);

  // final projection writes fp32 (reference output dtype is float32)
  gemm_out<<<dim3(M_ / BM, D_ / BN), 256, 0, stream>>>(Xm, wob, bo, (float*)d_out);
}